// Round 1
// baseline (76.928 us; speedup 1.0000x reference)
//
#include <hip/hip_runtime.h>
#include <stdint.h>

typedef short bf16x8 __attribute__((ext_vector_type(8)));
typedef float f32x4 __attribute__((ext_vector_type(4)));

#define NCI 128
#define NCO 128
#define HIN 64
#define NB  8

__device__ __forceinline__ unsigned short f32_to_bf16(float f) {
    union { float f; uint32_t u; } v; v.f = f;
    return (unsigned short)((v.u + 0x7FFFu + ((v.u >> 16) & 1u)) >> 16);
}

// Effective parity weights: Aw[par][co][k], k = tap*128 + ci, tap = ty*2+tx.
// Row sets S[p][t]: S[0][0]={0}, S[0][1]={1,2}, S[1][0]={0,1}, S[1][1]={2}
__global__ void weff_kernel(const float* __restrict__ W, unsigned short* __restrict__ Aw) {
    int idx = blockIdx.x * 256 + threadIdx.x;   // 4*128*512 = 262144 total
    int par = idx >> 16;
    int co  = (idx >> 9) & 127;
    int k   = idx & 511;
    int tap = k >> 7, ci = k & 127;
    int ty = tap >> 1, tx = tap & 1;
    int py = par >> 1, px = par & 1;
    const float* wp = W + (co * NCI + ci) * 9;
    float s = 0.f;
    #pragma unroll
    for (int ky = 0; ky < 3; ++ky) {
        bool iy = (py == 0) ? (ty == 0 ? (ky == 0) : (ky >= 1))
                            : (ty == 0 ? (ky <= 1) : (ky == 2));
        if (!iy) continue;
        #pragma unroll
        for (int kx = 0; kx < 3; ++kx) {
            bool ix = (px == 0) ? (tx == 0 ? (kx == 0) : (kx >= 1))
                                : (tx == 0 ? (kx <= 1) : (kx == 2));
            if (ix) s += wp[ky * 3 + kx];
        }
    }
    Aw[idx] = f32_to_bf16(s);
}

// GEMM per parity: C[co][s] = sum_{tap,ci} Weff[co][tap,ci] * xshift[tap,ci][s]
// Block: 128co x 128spatial, 4 waves (2x2), 4x4 16x16x32 fragments per wave.
__global__ __launch_bounds__(256) void upconv_kernel(
        const float* __restrict__ x, const unsigned short* __restrict__ Aw,
        const float* __restrict__ bv, float* __restrict__ out) {
    __shared__ __align__(16) unsigned short A_lds[128 * 32];  // [co][kk]
    __shared__ __align__(16) unsigned short B_lds[128 * 32];  // [n][kk]
    const int par = blockIdx.y, py = par >> 1, px = par & 1;
    const int tile = blockIdx.x;
    const int s0 = tile * 128;            // spatial base: (b, oy, ox) linear
    const int bimg = s0 >> 12;
    const int oy0 = (s0 >> 6) & 63;       // tile = 2 full ox-rows
    const int tid = threadIdx.x;
    const int lane = tid & 63, wave = tid >> 6;
    const int wm = wave >> 1, wn = wave & 1;
    const float* xb = x + bimg * (NCI * HIN * HIN);

    f32x4 acc[4][4];
    #pragma unroll
    for (int i = 0; i < 4; ++i)
        #pragma unroll
        for (int j = 0; j < 4; ++j)
            acc[i][j] = (f32x4){0.f, 0.f, 0.f, 0.f};

    for (int kt = 0; kt < 16; ++kt) {     // K = 512, BK = 32 (one tap, 32 ci)
        const int tap = kt >> 2, ci0 = (kt & 3) * 32;
        const int ty = tap >> 1, tx = tap & 1;

        // ---- stage A: 128co x 32k bf16 from precomputed Weff ----
        #pragma unroll
        for (int i = 0; i < 2; ++i) {
            int c = i * 256 + tid;        // 0..511: co = c>>2, 8-elem group g = c&3
            const bf16x8* src = (const bf16x8*)(Aw +
                ((par * 128 + (c >> 2)) * 512 + kt * 32 + (c & 3) * 8));
            *(bf16x8*)(&A_lds[c * 8]) = *src;
        }
        // ---- stage B: gather shifted x rows, cvt to bf16 ----
        #pragma unroll
        for (int i = 0; i < 2; ++i) {
            int tsk = i * 256 + tid;      // 0..511: n = tsk&127, 8-ci group kg
            int n = tsk & 127, kg = tsk >> 7;
            int r = n >> 6, ox = n & 63;
            int row = oy0 + r - 1 + py + ty;
            int col = ox - 1 + px + tx;
            bool ok = (row >= 0) & (row < HIN) & (col >= 0) & (col < HIN);
            const float* xp = xb + (((ci0 + kg * 8) * HIN + row) * HIN + col);
            bf16x8 v;
            #pragma unroll
            for (int q = 0; q < 8; ++q) {
                float f = ok ? xp[q * (HIN * HIN)] : 0.f;
                v[q] = (short)f32_to_bf16(f);
            }
            *(bf16x8*)(&B_lds[n * 32 + kg * 8]) = v;
        }
        __syncthreads();

        // ---- fragments + 16 MFMAs ----
        const int seg = (lane >> 4) * 8, rl = lane & 15;
        bf16x8 af[4], bfr[4];
        #pragma unroll
        for (int f = 0; f < 4; ++f)
            af[f] = *(const bf16x8*)(&A_lds[(wm * 64 + f * 16 + rl) * 32 + seg]);
        #pragma unroll
        for (int f = 0; f < 4; ++f)
            bfr[f] = *(const bf16x8*)(&B_lds[(wn * 64 + f * 16 + rl) * 32 + seg]);
        #pragma unroll
        for (int fm = 0; fm < 4; ++fm)
            #pragma unroll
            for (int fn = 0; fn < 4; ++fn)
                acc[fm][fn] = __builtin_amdgcn_mfma_f32_16x16x32_bf16(
                    af[fm], bfr[fn], acc[fm][fn], 0, 0, 0);
        __syncthreads();
    }

    // ---- epilogue: C/D layout col=lane&15 (n), row=(lane>>4)*4+j (co) ----
    #pragma unroll
    for (int fm = 0; fm < 4; ++fm) {
        const int co_b = wm * 64 + fm * 16 + (lane >> 4) * 4;
        float bias4[4];
        #pragma unroll
        for (int j = 0; j < 4; ++j) bias4[j] = bv[co_b + j];
        #pragma unroll
        for (int fn = 0; fn < 4; ++fn) {
            int n = wn * 64 + fn * 16 + (lane & 15);
            int s = s0 + n;
            int ox = s & 63, oy = (s >> 6) & 63, bi = s >> 12;
            int yy = 2 * oy + py, xx = 2 * ox + px;
            float* op = out + ((size_t)bi * 128 * 128 * 128) + (size_t)yy * 128 + xx;
            #pragma unroll
            for (int j = 0; j < 4; ++j)
                op[(size_t)(co_b + j) * (128 * 128)] = acc[fm][fn][j] + bias4[j];
        }
    }
}

extern "C" void kernel_launch(void* const* d_in, const int* in_sizes, int n_in,
                              void* d_out, int out_size, void* d_ws, size_t ws_size,
                              hipStream_t stream) {
    const float* x  = (const float*)d_in[0];
    const float* W  = (const float*)d_in[1];
    const float* bv = (const float*)d_in[2];
    float* out = (float*)d_out;
    unsigned short* Aw = (unsigned short*)d_ws;   // 512 KB scratch

    weff_kernel<<<1024, 256, 0, stream>>>(W, Aw);
    upconv_kernel<<<dim3(256, 4), 256, 0, stream>>>(x, Aw, bv, out);
}

// Round 2
// 61.040 us; speedup vs baseline: 1.2603x; 1.2603x over previous
//
#include <hip/hip_runtime.h>
#include <stdint.h>

typedef short bf16x8 __attribute__((ext_vector_type(8)));
typedef float f32x4 __attribute__((ext_vector_type(4)));

#define NCI 128
#define NCO 128
#define HIN 64
#define HP  66
#define NB  8

__device__ __forceinline__ unsigned short f32_to_bf16(float f) {
    union { float f; uint32_t u; } v; v.f = f;
    return (unsigned short)((v.u + 0x7FFFu + ((v.u >> 16) & 1u)) >> 16);
}

__device__ __forceinline__ void gl_lds16(const void* g, void* l) {
    __builtin_amdgcn_global_load_lds(
        (const __attribute__((address_space(1))) unsigned int*)g,
        (__attribute__((address_space(3))) unsigned int*)l, 16, 0, 0);
}

// Effective parity weights: Aw[par][co][k], k = tap*128 + ci, tap = ty*2+tx.
__global__ void weff_kernel(const float* __restrict__ W, unsigned short* __restrict__ Aw) {
    int idx = blockIdx.x * 256 + threadIdx.x;   // 4*128*512 = 262144 total
    int par = idx >> 16;
    int co  = (idx >> 9) & 127;
    int k   = idx & 511;
    int tap = k >> 7, ci = k & 127;
    int ty = tap >> 1, tx = tap & 1;
    int py = par >> 1, px = par & 1;
    const float* wp = W + (co * NCI + ci) * 9;
    float s = 0.f;
    #pragma unroll
    for (int ky = 0; ky < 3; ++ky) {
        bool iy = (py == 0) ? (ty == 0 ? (ky == 0) : (ky >= 1))
                            : (ty == 0 ? (ky <= 1) : (ky == 2));
        if (!iy) continue;
        #pragma unroll
        for (int kx = 0; kx < 3; ++kx) {
            bool ix = (px == 0) ? (tx == 0 ? (kx == 0) : (kx >= 1))
                                : (tx == 0 ? (kx <= 1) : (kx == 2));
            if (ix) s += wp[ky * 3 + kx];
        }
    }
    Aw[idx] = f32_to_bf16(s);
}

// x [8][128][64][64] f32  ->  xpad [8][66][66][128] bf16 (interior only; halo pre-zeroed)
__global__ __launch_bounds__(256) void pad_kernel(const float* __restrict__ x,
                                                  unsigned short* __restrict__ xp) {
    int b = blockIdx.x >> 6, h = blockIdx.x & 63;
    int t = threadIdx.x;
    int w = t & 63;
    int g0 = (t >> 6) * 4;
    const float* xb = x + ((size_t)b * NCI * HIN * HIN) + h * HIN + w;
    unsigned short* dst = xp + (((size_t)b * HP + (h + 1)) * HP + (w + 1)) * NCI;
    #pragma unroll
    for (int q = 0; q < 4; ++q) {
        int ci0 = (g0 + q) * 8;
        bf16x8 v;
        #pragma unroll
        for (int j = 0; j < 8; ++j)
            v[j] = (short)f32_to_bf16(xb[(size_t)(ci0 + j) * (HIN * HIN)]);
        *(bf16x8*)(dst + ci0) = v;
    }
}

// Main GEMM: per (tile, py) block, both px parities. 8 waves: pxw = wv>>2, 2x2 wave grid.
// A/B tiles 128x32 bf16, XOR-swizzled (part ^= (row>>1)&3), staged via global_load_lds x16.
__global__ __launch_bounds__(512, 2) void upconv2_kernel(
        const unsigned short* __restrict__ xpad, const unsigned short* __restrict__ Aw,
        const float* __restrict__ bv, float* __restrict__ out) {
    __shared__ __align__(16) unsigned short A_lds[2][128 * 32];
    __shared__ __align__(16) unsigned short B_lds[2][128 * 32];
    const int tile = blockIdx.x, py = blockIdx.y;
    const int s0 = tile * 128;
    const int bi = s0 >> 12;
    const int oy0 = (s0 >> 6) & 63;
    const int tid = threadIdx.x, lane = tid & 63, wv = tid >> 6;
    const int pxw = wv >> 2, wm = (wv >> 1) & 1, wn = wv & 1;
    const unsigned short* xb = xpad + (size_t)bi * (HP * HP * NCI);

    // staging: thread -> (row, part); load logical partL into physical slot
    const int srow = tid >> 2;
    const int spartL = (tid & 3) ^ ((srow >> 1) & 3);
    const int br = srow >> 6, box = srow & 63;
    const int boy = oy0 + br;

    f32x4 acc[4][4];
    #pragma unroll
    for (int i = 0; i < 4; ++i)
        #pragma unroll
        for (int j = 0; j < 4; ++j)
            acc[i][j] = (f32x4){0.f, 0.f, 0.f, 0.f};

    for (int kt = 0; kt < 16; ++kt) {
        const int tap = kt >> 2, ci0k = (kt & 3) * 32;
        const int ty = tap >> 1, tx = tap & 1;
        // A tiles (px = 0,1)
        #pragma unroll
        for (int px = 0; px < 2; ++px) {
            const unsigned short* ga =
                Aw + (((py * 2 + px) * 128 + srow) * 512 + kt * 32 + spartL * 8);
            gl_lds16(ga, &A_lds[px][tid * 8]);
        }
        // B tiles (px = 0,1): xpad[bi][boy+py+ty][box+px+tx][ci0k + partL*8 ..]
        const int rowg = boy + py + ty;
        #pragma unroll
        for (int px = 0; px < 2; ++px) {
            const int colg = box + px + tx;
            const unsigned short* gb =
                xb + ((size_t)(rowg * HP + colg)) * NCI + ci0k + spartL * 8;
            gl_lds16(gb, &B_lds[px][tid * 8]);
        }
        __syncthreads();

        const int rl = lane & 15, pl = lane >> 4;
        bf16x8 af[4], bfr[4];
        #pragma unroll
        for (int f = 0; f < 4; ++f) {
            int ar = wm * 64 + f * 16 + rl;
            af[f] = *(const bf16x8*)&A_lds[pxw][ar * 32 + ((pl ^ ((ar >> 1) & 3)) * 8)];
            int bn = wn * 64 + f * 16 + rl;
            bfr[f] = *(const bf16x8*)&B_lds[pxw][bn * 32 + ((pl ^ ((bn >> 1) & 3)) * 8)];
        }
        #pragma unroll
        for (int fm = 0; fm < 4; ++fm)
            #pragma unroll
            for (int fn = 0; fn < 4; ++fn)
                acc[fm][fn] = __builtin_amdgcn_mfma_f32_16x16x32_bf16(
                    af[fm], bfr[fn], acc[fm][fn], 0, 0, 0);
        __syncthreads();
    }

    // epilogue: C/D layout col=lane&15 (n), row=(lane>>4)*4+j (co)
    #pragma unroll
    for (int fm = 0; fm < 4; ++fm) {
        const int co_b = wm * 64 + fm * 16 + (lane >> 4) * 4;
        float b4[4];
        #pragma unroll
        for (int j = 0; j < 4; ++j) b4[j] = bv[co_b + j];
        #pragma unroll
        for (int fn = 0; fn < 4; ++fn) {
            int n = wn * 64 + fn * 16 + (lane & 15);
            int ox = n & 63, r = n >> 6;
            int yy = 2 * (oy0 + r) + py, xx = 2 * ox + pxw;
            float* op = out + (((size_t)bi * NCO + co_b) * (128 * 128)) + yy * 128 + xx;
            #pragma unroll
            for (int j = 0; j < 4; ++j)
                op[(size_t)j * (128 * 128)] = acc[fm][fn][j] + b4[j];
        }
    }
}

// -------- round-1 fallback (used only if ws_size too small) --------
__global__ __launch_bounds__(256) void upconv_kernel(
        const float* __restrict__ x, const unsigned short* __restrict__ Aw,
        const float* __restrict__ bv, float* __restrict__ out) {
    __shared__ __align__(16) unsigned short A_lds[128 * 32];
    __shared__ __align__(16) unsigned short B_lds[128 * 32];
    const int par = blockIdx.y, py = par >> 1, px = par & 1;
    const int tile = blockIdx.x;
    const int s0 = tile * 128;
    const int bimg = s0 >> 12;
    const int oy0 = (s0 >> 6) & 63;
    const int tid = threadIdx.x;
    const int lane = tid & 63, wave = tid >> 6;
    const int wm = wave >> 1, wn = wave & 1;
    const float* xb = x + bimg * (NCI * HIN * HIN);

    f32x4 acc[4][4];
    #pragma unroll
    for (int i = 0; i < 4; ++i)
        #pragma unroll
        for (int j = 0; j < 4; ++j)
            acc[i][j] = (f32x4){0.f, 0.f, 0.f, 0.f};

    for (int kt = 0; kt < 16; ++kt) {
        const int tap = kt >> 2, ci0 = (kt & 3) * 32;
        const int ty = tap >> 1, tx = tap & 1;
        #pragma unroll
        for (int i = 0; i < 2; ++i) {
            int c = i * 256 + tid;
            const bf16x8* src = (const bf16x8*)(Aw +
                ((par * 128 + (c >> 2)) * 512 + kt * 32 + (c & 3) * 8));
            *(bf16x8*)(&A_lds[c * 8]) = *src;
        }
        #pragma unroll
        for (int i = 0; i < 2; ++i) {
            int tsk = i * 256 + tid;
            int n = tsk & 127, kg = tsk >> 7;
            int r = n >> 6, ox = n & 63;
            int row = oy0 + r - 1 + py + ty;
            int col = ox - 1 + px + tx;
            bool ok = (row >= 0) & (row < HIN) & (col >= 0) & (col < HIN);
            const float* xp = xb + (((ci0 + kg * 8) * HIN + row) * HIN + col);
            bf16x8 v;
            #pragma unroll
            for (int q = 0; q < 8; ++q) {
                float f = ok ? xp[q * (HIN * HIN)] : 0.f;
                v[q] = (short)f32_to_bf16(f);
            }
            *(bf16x8*)(&B_lds[n * 32 + kg * 8]) = v;
        }
        __syncthreads();
        const int seg = (lane >> 4) * 8, rl = lane & 15;
        bf16x8 af[4], bfr[4];
        #pragma unroll
        for (int f = 0; f < 4; ++f)
            af[f] = *(const bf16x8*)(&A_lds[(wm * 64 + f * 16 + rl) * 32 + seg]);
        #pragma unroll
        for (int f = 0; f < 4; ++f)
            bfr[f] = *(const bf16x8*)(&B_lds[(wn * 64 + f * 16 + rl) * 32 + seg]);
        #pragma unroll
        for (int fm = 0; fm < 4; ++fm)
            #pragma unroll
            for (int fn = 0; fn < 4; ++fn)
                acc[fm][fn] = __builtin_amdgcn_mfma_f32_16x16x32_bf16(
                    af[fm], bfr[fn], acc[fm][fn], 0, 0, 0);
        __syncthreads();
    }
    #pragma unroll
    for (int fm = 0; fm < 4; ++fm) {
        const int co_b = wm * 64 + fm * 16 + (lane >> 4) * 4;
        float bias4[4];
        #pragma unroll
        for (int j = 0; j < 4; ++j) bias4[j] = bv[co_b + j];
        #pragma unroll
        for (int fn = 0; fn < 4; ++fn) {
            int n = wn * 64 + fn * 16 + (lane & 15);
            int s = s0 + n;
            int ox = s & 63, oy = (s >> 6) & 63, bi2 = s >> 12;
            int yy = 2 * oy + py, xx = 2 * ox + px;
            float* op = out + ((size_t)bi2 * 128 * 128 * 128) + (size_t)yy * 128 + xx;
            #pragma unroll
            for (int j = 0; j < 4; ++j)
                op[(size_t)(co_b + j) * (128 * 128)] = acc[fm][fn][j] + bias4[j];
        }
    }
}

extern "C" void kernel_launch(void* const* d_in, const int* in_sizes, int n_in,
                              void* d_out, int out_size, void* d_ws, size_t ws_size,
                              hipStream_t stream) {
    const float* x  = (const float*)d_in[0];
    const float* W  = (const float*)d_in[1];
    const float* bv = (const float*)d_in[2];
    float* out = (float*)d_out;
    unsigned short* Aw = (unsigned short*)d_ws;               // 512 KB
    const size_t aw_bytes = 4 * 128 * 512 * sizeof(unsigned short);
    const size_t xpad_bytes = (size_t)NB * HP * HP * NCI * sizeof(unsigned short);

    if (ws_size >= aw_bytes + xpad_bytes) {
        unsigned short* xpad = (unsigned short*)((char*)d_ws + aw_bytes);
        hipMemsetAsync(xpad, 0, xpad_bytes, stream);
        weff_kernel<<<1024, 256, 0, stream>>>(W, Aw);
        pad_kernel<<<512, 256, 0, stream>>>(x, xpad);
        upconv2_kernel<<<dim3(256, 2), 512, 0, stream>>>(xpad, Aw, bv, out);
    } else {
        weff_kernel<<<1024, 256, 0, stream>>>(W, Aw);
        upconv_kernel<<<dim3(256, 4), 256, 0, stream>>>(x, Aw, bv, out);
    }
}

// Round 3
// 57.540 us; speedup vs baseline: 1.3369x; 1.0608x over previous
//
#include <hip/hip_runtime.h>
#include <stdint.h>

typedef short bf16x8 __attribute__((ext_vector_type(8)));
typedef float f32x4 __attribute__((ext_vector_type(4)));
typedef unsigned int u32x4 __attribute__((ext_vector_type(4)));

#define NCI 128
#define NCO 128
#define HIN 64
#define HP  66
#define NB  8

__device__ __forceinline__ unsigned short f32_to_bf16(float f) {
    union { float f; uint32_t u; } v; v.f = f;
    return (unsigned short)((v.u + 0x7FFFu + ((v.u >> 16) & 1u)) >> 16);
}

__device__ __forceinline__ void gl_lds16(const void* g, void* l) {
    __builtin_amdgcn_global_load_lds(
        (const __attribute__((address_space(1))) unsigned int*)g,
        (__attribute__((address_space(3))) unsigned int*)l, 16, 0, 0);
}

__device__ __forceinline__ void vmw0() {
    asm volatile("s_waitcnt vmcnt(0)" ::: "memory");
}
__device__ __forceinline__ void lkw0() {
    asm volatile("s_waitcnt lgkmcnt(0)" ::: "memory");
}
__device__ __forceinline__ void barx() {
    asm volatile("" ::: "memory");
    __builtin_amdgcn_s_barrier();
    asm volatile("" ::: "memory");
}

// Effective parity weights: Aw[par][co][k], k = tap*128 + ci, tap = ty*2+tx.
__global__ void weff_kernel(const float* __restrict__ W, unsigned short* __restrict__ Aw) {
    int idx = blockIdx.x * 256 + threadIdx.x;   // 4*128*512 = 262144 total
    int par = idx >> 16;
    int co  = (idx >> 9) & 127;
    int k   = idx & 511;
    int tap = k >> 7, ci = k & 127;
    int ty = tap >> 1, tx = tap & 1;
    int py = par >> 1, px = par & 1;
    const float* wp = W + (co * NCI + ci) * 9;
    float s = 0.f;
    #pragma unroll
    for (int ky = 0; ky < 3; ++ky) {
        bool iy = (py == 0) ? (ty == 0 ? (ky == 0) : (ky >= 1))
                            : (ty == 0 ? (ky <= 1) : (ky == 2));
        if (!iy) continue;
        #pragma unroll
        for (int kx = 0; kx < 3; ++kx) {
            bool ix = (px == 0) ? (tx == 0 ? (kx == 0) : (kx >= 1))
                                : (tx == 0 ? (kx <= 1) : (kx == 2));
            if (ix) s += wp[ky * 3 + kx];
        }
    }
    Aw[idx] = f32_to_bf16(s);
}

// x [8][128][64][64] f32 -> xpad [8][66][66][128] bf16, halo written here (no memset).
__global__ __launch_bounds__(256) void pad_kernel(const float* __restrict__ x,
                                                  unsigned short* __restrict__ xp) {
    const int b = blockIdx.x / HP, hp = blockIdx.x % HP;   // hp 0..65
    const int t = threadIdx.x;
    unsigned short* rowp = xp + ((size_t)b * HP + hp) * HP * NCI;
    if (hp == 0 || hp == HP - 1) {
        u32x4 z = (u32x4){0, 0, 0, 0};
        for (int i = t; i < (HP * NCI) / 8; i += 256) ((u32x4*)rowp)[i] = z;
        return;
    }
    const int h = hp - 1;
    if (t < 32) {   // column halo wp=0, wp=65
        u32x4 z = (u32x4){0, 0, 0, 0};
        int wp = (t >> 4) ? (HP - 1) : 0;
        ((u32x4*)(rowp + wp * NCI))[t & 15] = z;
    }
    const int w = t & 63;
    const int g0 = (t >> 6) * 4;
    const float* xb = x + ((size_t)b * NCI * HIN * HIN) + h * HIN + w;
    unsigned short* dst = rowp + (w + 1) * NCI;
    #pragma unroll
    for (int q = 0; q < 4; ++q) {
        int ci0 = (g0 + q) * 8;
        bf16x8 v;
        #pragma unroll
        for (int j = 0; j < 8; ++j)
            v[j] = (short)f32_to_bf16(xb[(size_t)(ci0 + j) * (HIN * HIN)]);
        *(bf16x8*)(dst + ci0) = v;
    }
}

// Main GEMM: 2-phase double-buffered pipeline + LDS-coalesced epilogue.
// Block: (tile, py), 512 thr = 8 waves: pxw = wv>>2, 2x2 wave grid (wm, wn).
__global__ __launch_bounds__(512, 2) void upconv3_kernel(
        const unsigned short* __restrict__ xpad, const unsigned short* __restrict__ Aw,
        const float* __restrict__ bv, float* __restrict__ out) {
    __shared__ __align__(16) unsigned short smem[32768];   // 64 KB: A[2][2][4096] | B[2][2][4096]
    unsigned short* sA = smem;
    unsigned short* sB = smem + 16384;
    const int tile = blockIdx.x, py = blockIdx.y;
    const int s0 = tile * 128;
    const int bi = s0 >> 12;
    const int oy0 = (s0 >> 6) & 63;
    const int tid = threadIdx.x, lane = tid & 63, wv = tid >> 6;
    const int pxw = wv >> 2, wm = (wv >> 1) & 1, wn = wv & 1;
    const unsigned short* xb = xpad + (size_t)bi * (HP * HP * NCI);

    // staging map: thread -> physical slot tid*8; logical (row=tid>>2, part=(tid&3)^swz)
    const int srow = tid >> 2;
    const int spartL = (tid & 3) ^ ((srow >> 1) & 3);
    const int box = srow & 63;
    const int boy = oy0 + (srow >> 6);

    f32x4 acc[4][4];
    #pragma unroll
    for (int i = 0; i < 4; ++i)
        #pragma unroll
        for (int j = 0; j < 4; ++j)
            acc[i][j] = (f32x4){0.f, 0.f, 0.f, 0.f};

    auto stage = [&](int buf, int kt2) {
        const int tap = kt2 >> 2, ci0k = (kt2 & 3) * 32;
        const int ty = tap >> 1, tx = tap & 1;
        const int rowg = boy + py + ty;
        #pragma unroll
        for (int px = 0; px < 2; ++px) {
            const unsigned short* ga =
                Aw + (((py * 2 + px) * 128 + srow) * 512 + kt2 * 32 + spartL * 8);
            gl_lds16(ga, &sA[(buf * 2 + px) * 4096 + tid * 8]);
            const int colg = box + px + tx;
            const unsigned short* gb =
                xb + ((size_t)(rowg * HP + colg)) * NCI + ci0k + spartL * 8;
            gl_lds16(gb, &sB[(buf * 2 + px) * 4096 + tid * 8]);
        }
    };

    const int rl = lane & 15, pl = lane >> 4;

    stage(0, 0);
    vmw0();
    barx();

    int cur = 0;
    for (int kt = 0; kt < 16; ++kt) {
        if (kt < 15) stage(cur ^ 1, kt + 1);
        bf16x8 af[4], bfr[4];
        #pragma unroll
        for (int f = 0; f < 4; ++f) {
            int ar = wm * 64 + f * 16 + rl;
            af[f] = *(const bf16x8*)&sA[(cur * 2 + pxw) * 4096 + ar * 32 +
                                        ((pl ^ ((ar >> 1) & 3)) * 8)];
            int bn = wn * 64 + f * 16 + rl;
            bfr[f] = *(const bf16x8*)&sB[(cur * 2 + pxw) * 4096 + bn * 32 +
                                         ((pl ^ ((bn >> 1) & 3)) * 8)];
        }
        #pragma unroll
        for (int fm = 0; fm < 4; ++fm)
            #pragma unroll
            for (int fn = 0; fn < 4; ++fn)
                acc[fm][fn] = __builtin_amdgcn_mfma_f32_16x16x32_bf16(
                    af[fm], bfr[fn], acc[fm][fn], 0, 0, 0);
        vmw0();          // next tile's loads landed (issued before compute phase)
        barx();
        cur ^= 1;
    }

    // ---- coalesced epilogue via LDS: lf[co_l 0..31][r 0..1][xx 0..127], stride 264 ----
    float* lf = (float*)smem;
    const int co_l = tid >> 4;
    const int rem = tid & 15, rr = rem >> 3, x16 = (rem & 7) * 16;
    const int co_g = (co_l >> 4) * 64 + (co_l & 15);
    const int yy = 2 * (oy0 + rr) + py;

    #pragma unroll
    for (int fm = 0; fm < 4; ++fm) {
        #pragma unroll
        for (int fn = 0; fn < 4; ++fn) {
            int n = wn * 64 + fn * 16 + rl;
            int r = n >> 6, xx = 2 * (n & 63) + pxw;
            #pragma unroll
            for (int j = 0; j < 4; ++j) {
                int col = wm * 16 + pl * 4 + j;
                lf[col * 264 + r * 132 + xx] = acc[fm][fn][j];
            }
        }
        lkw0();
        barx();
        const int co = co_g + fm * 16;
        const float bb = bv[co];
        float* op = out + (((size_t)bi * NCO + co) * 128 + yy) * 128 + x16;
        const float* sp = lf + co_l * 264 + rr * 132 + x16;
        #pragma unroll
        for (int q = 0; q < 4; ++q) {
            f32x4 v = *(const f32x4*)(sp + q * 4);
            v[0] += bb; v[1] += bb; v[2] += bb; v[3] += bb;
            *(f32x4*)(op + q * 4) = v;
        }
        if (fm < 3) barx();
    }
}

// -------- fallback (ws too small): round-1 kernel, reads x directly --------
__global__ __launch_bounds__(256) void upconv_kernel(
        const float* __restrict__ x, const unsigned short* __restrict__ Aw,
        const float* __restrict__ bv, float* __restrict__ out) {
    __shared__ __align__(16) unsigned short A_lds[128 * 32];
    __shared__ __align__(16) unsigned short B_lds[128 * 32];
    const int par = blockIdx.y, py = par >> 1, px = par & 1;
    const int s0 = blockIdx.x * 128;
    const int bimg = s0 >> 12;
    const int oy0 = (s0 >> 6) & 63;
    const int tid = threadIdx.x;
    const int lane = tid & 63, wave = tid >> 6;
    const int wm = wave >> 1, wn = wave & 1;
    const float* xb = x + bimg * (NCI * HIN * HIN);
    f32x4 acc[4][4];
    #pragma unroll
    for (int i = 0; i < 4; ++i)
        #pragma unroll
        for (int j = 0; j < 4; ++j)
            acc[i][j] = (f32x4){0.f, 0.f, 0.f, 0.f};
    for (int kt = 0; kt < 16; ++kt) {
        const int tap = kt >> 2, ci0 = (kt & 3) * 32;
        const int ty = tap >> 1, tx = tap & 1;
        #pragma unroll
        for (int i = 0; i < 2; ++i) {
            int c = i * 256 + tid;
            const bf16x8* src = (const bf16x8*)(Aw +
                ((par * 128 + (c >> 2)) * 512 + kt * 32 + (c & 3) * 8));
            *(bf16x8*)(&A_lds[c * 8]) = *src;
        }
        #pragma unroll
        for (int i = 0; i < 2; ++i) {
            int tsk = i * 256 + tid;
            int n = tsk & 127, kg = tsk >> 7;
            int r = n >> 6, ox = n & 63;
            int row = oy0 + r - 1 + py + ty;
            int col = ox - 1 + px + tx;
            bool ok = (row >= 0) & (row < HIN) & (col >= 0) & (col < HIN);
            const float* xp = xb + (((ci0 + kg * 8) * HIN + row) * HIN + col);
            bf16x8 v;
            #pragma unroll
            for (int q = 0; q < 8; ++q) {
                float f = ok ? xp[q * (HIN * HIN)] : 0.f;
                v[q] = (short)f32_to_bf16(f);
            }
            *(bf16x8*)(&B_lds[n * 32 + kg * 8]) = v;
        }
        __syncthreads();
        const int seg = (lane >> 4) * 8, rl2 = lane & 15;
        bf16x8 af[4], bfr[4];
        #pragma unroll
        for (int f = 0; f < 4; ++f)
            af[f] = *(const bf16x8*)(&A_lds[(wm * 64 + f * 16 + rl2) * 32 + seg]);
        #pragma unroll
        for (int f = 0; f < 4; ++f)
            bfr[f] = *(const bf16x8*)(&B_lds[(wn * 64 + f * 16 + rl2) * 32 + seg]);
        #pragma unroll
        for (int fm = 0; fm < 4; ++fm)
            #pragma unroll
            for (int fn = 0; fn < 4; ++fn)
                acc[fm][fn] = __builtin_amdgcn_mfma_f32_16x16x32_bf16(
                    af[fm], bfr[fn], acc[fm][fn], 0, 0, 0);
        __syncthreads();
    }
    #pragma unroll
    for (int fm = 0; fm < 4; ++fm) {
        const int co_b = wm * 64 + fm * 16 + (lane >> 4) * 4;
        float bias4[4];
        #pragma unroll
        for (int j = 0; j < 4; ++j) bias4[j] = bv[co_b + j];
        #pragma unroll
        for (int fn = 0; fn < 4; ++fn) {
            int n = wn * 64 + fn * 16 + (lane & 15);
            int s = s0 + n;
            int ox = s & 63, oy = (s >> 6) & 63, bi2 = s >> 12;
            int yy = 2 * oy + py, xx = 2 * ox + px;
            float* op = out + ((size_t)bi2 * 128 * 128 * 128) + (size_t)yy * 128 + xx;
            #pragma unroll
            for (int j = 0; j < 4; ++j)
                op[(size_t)(co_b + j) * (128 * 128)] = acc[fm][fn][j] + bias4[j];
        }
    }
}

extern "C" void kernel_launch(void* const* d_in, const int* in_sizes, int n_in,
                              void* d_out, int out_size, void* d_ws, size_t ws_size,
                              hipStream_t stream) {
    const float* x  = (const float*)d_in[0];
    const float* W  = (const float*)d_in[1];
    const float* bv = (const float*)d_in[2];
    float* out = (float*)d_out;
    unsigned short* Aw = (unsigned short*)d_ws;               // 512 KB
    const size_t aw_bytes = 4 * 128 * 512 * sizeof(unsigned short);
    const size_t xpad_bytes = (size_t)NB * HP * HP * NCI * sizeof(unsigned short);

    if (ws_size >= aw_bytes + xpad_bytes) {
        unsigned short* xpad = (unsigned short*)((char*)d_ws + aw_bytes);
        weff_kernel<<<1024, 256, 0, stream>>>(W, Aw);
        pad_kernel<<<NB * HP, 256, 0, stream>>>(x, xpad);
        upconv3_kernel<<<dim3(256, 2), 512, 0, stream>>>(xpad, Aw, bv, out);
    } else {
        weff_kernel<<<1024, 256, 0, stream>>>(W, Aw);
        upconv_kernel<<<dim3(256, 4), 256, 0, stream>>>(x, Aw, bv, out);
    }
}

// Round 4
// 49.107 us; speedup vs baseline: 1.5665x; 1.1717x over previous
//
#include <hip/hip_runtime.h>
#include <stdint.h>

typedef short bf16x8 __attribute__((ext_vector_type(8)));
typedef float f32x4 __attribute__((ext_vector_type(4)));
typedef unsigned int u32x4 __attribute__((ext_vector_type(4)));

#define NCI 128
#define NCO 128
#define HIN 64
#define HP  66
#define NB  8

__device__ __forceinline__ unsigned short f32_to_bf16(float f) {
    union { float f; uint32_t u; } v; v.f = f;
    return (unsigned short)((v.u + 0x7FFFu + ((v.u >> 16) & 1u)) >> 16);
}

__device__ __forceinline__ void gl_lds16(const void* g, void* l) {
    __builtin_amdgcn_global_load_lds(
        (const __attribute__((address_space(1))) unsigned int*)g,
        (__attribute__((address_space(3))) unsigned int*)l, 16, 0, 0);
}

__device__ __forceinline__ void vmw0() {
    asm volatile("s_waitcnt vmcnt(0)" ::: "memory");
}
__device__ __forceinline__ void lkw0() {
    asm volatile("s_waitcnt lgkmcnt(0)" ::: "memory");
}
__device__ __forceinline__ void barx() {
    asm volatile("" ::: "memory");
    __builtin_amdgcn_s_barrier();
    asm volatile("" ::: "memory");
}

// ---- fused prologue ----
// blocks [0,1024): Weff -> Aw2[par][kt][row][pp][8], tile-major, XOR pre-swizzled.
//   content(par,kt,row,pp,e) = Weff[par][co=row][k = kt*32 + (pp ^ ((row>>1)&3))*8 + e]
// blocks [1024,1552): x [8][128][64][64] f32 -> xq [8][4][66][66][32] bf16 (chunked NHWC,
//   halo written here).
__global__ __launch_bounds__(256) void prep_kernel(
        const float* __restrict__ W, const float* __restrict__ x,
        unsigned short* __restrict__ Aw2, unsigned short* __restrict__ xq) {
    if (blockIdx.x < 1024) {
        int idx = blockIdx.x * 256 + threadIdx.x;     // 262144 total
        int e   = idx & 7;
        int pp  = (idx >> 3) & 3;
        int row = (idx >> 5) & 127;
        int kt  = (idx >> 12) & 15;
        int par = idx >> 16;
        int k   = kt * 32 + ((pp ^ ((row >> 1) & 3)) * 8) + e;
        int tap = k >> 7, ci = k & 127;
        int ty = tap >> 1, tx = tap & 1;
        int py = par >> 1, px = par & 1;
        const float* wp = W + (row * NCI + ci) * 9;
        float s = 0.f;
        #pragma unroll
        for (int ky = 0; ky < 3; ++ky) {
            bool iy = (py == 0) ? (ty == 0 ? (ky == 0) : (ky >= 1))
                                : (ty == 0 ? (ky <= 1) : (ky == 2));
            if (!iy) continue;
            #pragma unroll
            for (int kx = 0; kx < 3; ++kx) {
                bool ix = (px == 0) ? (tx == 0 ? (kx == 0) : (kx >= 1))
                                    : (tx == 0 ? (kx <= 1) : (kx == 2));
                if (ix) s += wp[ky * 3 + kx];
            }
        }
        Aw2[idx] = f32_to_bf16(s);
    } else {
        const int bb = blockIdx.x - 1024;             // 528 blocks
        const int b = bb / HP, hp = bb % HP;
        const int t = threadIdx.x;
        if (hp == 0 || hp == HP - 1) {                // top/bottom halo rows, all 4 chunks
            bf16x8 z = (bf16x8){0, 0, 0, 0, 0, 0, 0, 0};
            for (int i = t; i < 4 * HP * 4; i += 256) {   // 4g * 66wp * (32elem=4x8)
                int g = i / (HP * 4), rem = i % (HP * 4);
                unsigned short* dst = xq +
                    ((((size_t)(b * 4 + g) * HP + hp) * HP) << 5) + rem * 8;
                *(bf16x8*)dst = z;
            }
            return;
        }
        const int h = hp - 1;
        if (t < 32) {                                  // column halo wp = 0, 65
            bf16x8 z = (bf16x8){0, 0, 0, 0, 0, 0, 0, 0};
            int g = t >> 3, wpc = ((t >> 2) & 1) * (HP - 1), q = t & 3;
            unsigned short* dst = xq +
                ((((size_t)(b * 4 + g) * HP + hp) * HP + wpc) << 5) + q * 8;
            *(bf16x8*)dst = z;
        }
        const int w = t & 63, g = t >> 6;
        const float* src = x + ((size_t)(b * NCI + g * 32) * (HIN * HIN)) + h * HIN + w;
        unsigned short* dst = xq +
            ((((size_t)(b * 4 + g) * HP + hp) * HP + (w + 1)) << 5);
        #pragma unroll
        for (int q = 0; q < 4; ++q) {
            bf16x8 v;
            #pragma unroll
            for (int j = 0; j < 8; ++j)
                v[j] = (short)f32_to_bf16(src[(size_t)(q * 8 + j) * (HIN * HIN)]);
            *(bf16x8*)(dst + q * 8) = v;
        }
    }
}

// Main GEMM: 2-phase double-buffered pipeline, fully-coalesced gl_lds staging,
// LDS-coalesced epilogue. Block: (tile, py), 512 thr = 8 waves (pxw, wm, wn).
__global__ __launch_bounds__(512, 2) void upconv4_kernel(
        const unsigned short* __restrict__ xq, const unsigned short* __restrict__ Aw2,
        const float* __restrict__ bv, float* __restrict__ out) {
    __shared__ __align__(16) unsigned short smem[32768];   // 64 KB
    unsigned short* sA = smem;
    unsigned short* sB = smem + 16384;
    // bijective XCD chunk swizzle (512 % 8 == 0)
    const int d = blockIdx.x;
    const int ds = (d & 7) * 64 + (d >> 3);
    const int tile = ds >> 1, py = ds & 1;
    const int bi = tile >> 5;
    const int oy0 = (tile & 31) * 2;
    const int tid = threadIdx.x, lane = tid & 63, wv = tid >> 6;
    const int pxw = wv >> 2, wm = (wv >> 1) & 1, wn = wv & 1;

    // staging map: physical LDS slot tid*8 <-> (row = tid>>2, pp = tid&3);
    // source supplies logical part pp ^ ((row>>1)&3)
    const int srow = tid >> 2;
    const int pL = (tid & 3) ^ ((srow >> 1) & 3);
    const int box = srow & 63;
    const int boy = oy0 + (srow >> 6);

    f32x4 acc[4][4];
    #pragma unroll
    for (int i = 0; i < 4; ++i)
        #pragma unroll
        for (int j = 0; j < 4; ++j)
            acc[i][j] = (f32x4){0.f, 0.f, 0.f, 0.f};

    auto stage = [&](int buf, int kt2) {
        const int g = kt2 & 3, tx = (kt2 >> 2) & 1, ty = kt2 >> 3;
        const int rowg = boy + py + ty;
        #pragma unroll
        for (int px = 0; px < 2; ++px) {
            // A: one contiguous 8KB tile; wave reads 1KB linear
            const unsigned short* ga =
                Aw2 + ((((py * 2 + px) * 16 + kt2) << 12)) + tid * 8;
            gl_lds16(ga, &sA[(buf * 2 + px) * 4096 + tid * 8]);
            // B: chunked xq; wave reads 1KB linear (16B-permuted within 64B)
            const int wpn = box + px + tx;
            const unsigned short* gb = xq +
                ((((size_t)(bi * 4 + g) * HP + rowg) * HP + wpn) << 5) + pL * 8;
            gl_lds16(gb, &sB[(buf * 2 + px) * 4096 + tid * 8]);
        }
    };

    const int rl = lane & 15, pl = lane >> 4;

    stage(0, 0);
    vmw0();
    barx();

    int cur = 0;
    for (int kt = 0; kt < 16; ++kt) {
        if (kt < 15) stage(cur ^ 1, kt + 1);
        bf16x8 af[4], bfr[4];
        #pragma unroll
        for (int f = 0; f < 4; ++f) {
            int ar = wm * 64 + f * 16 + rl;
            af[f] = *(const bf16x8*)&sA[(cur * 2 + pxw) * 4096 + ar * 32 +
                                        ((pl ^ ((ar >> 1) & 3)) * 8)];
            int bn = wn * 64 + f * 16 + rl;
            bfr[f] = *(const bf16x8*)&sB[(cur * 2 + pxw) * 4096 + bn * 32 +
                                         ((pl ^ ((bn >> 1) & 3)) * 8)];
        }
        #pragma unroll
        for (int fm = 0; fm < 4; ++fm)
            #pragma unroll
            for (int fn = 0; fn < 4; ++fn)
                acc[fm][fn] = __builtin_amdgcn_mfma_f32_16x16x32_bf16(
                    af[fm], bfr[fn], acc[fm][fn], 0, 0, 0);
        vmw0();
        barx();
        cur ^= 1;
    }

    // coalesced epilogue via LDS: lf[co_l 0..31][r 0..1][xx 0..127], stride 264
    float* lf = (float*)smem;
    const int co_l = tid >> 4;
    const int rem = tid & 15, rr = rem >> 3, x16 = (rem & 7) * 16;
    const int co_g = (co_l >> 4) * 64 + (co_l & 15);
    const int yy = 2 * (oy0 + rr) + py;

    #pragma unroll
    for (int fm = 0; fm < 4; ++fm) {
        #pragma unroll
        for (int fn = 0; fn < 4; ++fn) {
            int n = wn * 64 + fn * 16 + rl;
            int r = n >> 6, xx = 2 * (n & 63) + pxw;
            #pragma unroll
            for (int j = 0; j < 4; ++j) {
                int col = wm * 16 + pl * 4 + j;
                lf[col * 264 + r * 132 + xx] = acc[fm][fn][j];
            }
        }
        lkw0();
        barx();
        const int co = co_g + fm * 16;
        const float bb = bv[co];
        float* op = out + (((size_t)bi * NCO + co) * 128 + yy) * 128 + x16;
        const float* sp = lf + co_l * 264 + rr * 132 + x16;
        #pragma unroll
        for (int q = 0; q < 4; ++q) {
            f32x4 v = *(const f32x4*)(sp + q * 4);
            v[0] += bb; v[1] += bb; v[2] += bb; v[3] += bb;
            *(f32x4*)(op + q * 4) = v;
        }
        if (fm < 3) barx();
    }
}

// -------- fallback (ws too small for xpad): reads x f32 directly, new Aw2 layout --------
__global__ __launch_bounds__(256) void upconv_fb_kernel(
        const float* __restrict__ x, const unsigned short* __restrict__ Aw2,
        const float* __restrict__ bv, float* __restrict__ out) {
    __shared__ __align__(16) unsigned short A_lds[128 * 32];
    __shared__ __align__(16) unsigned short B_lds[128 * 32];
    const int par = blockIdx.y, py = par >> 1, px = par & 1;
    const int s0 = blockIdx.x * 128;
    const int bimg = s0 >> 12;
    const int oy0 = (s0 >> 6) & 63;
    const int tid = threadIdx.x;
    const int lane = tid & 63, wave = tid >> 6;
    const int wm = wave >> 1, wn = wave & 1;
    const float* xb = x + bimg * (NCI * HIN * HIN);
    f32x4 acc[4][4];
    #pragma unroll
    for (int i = 0; i < 4; ++i)
        #pragma unroll
        for (int j = 0; j < 4; ++j)
            acc[i][j] = (f32x4){0.f, 0.f, 0.f, 0.f};
    for (int kt = 0; kt < 16; ++kt) {
        const int tap = kt >> 2, ci0 = (kt & 3) * 32;
        const int ty = tap >> 1, tx = tap & 1;
        #pragma unroll
        for (int i = 0; i < 2; ++i) {
            int c = i * 256 + tid;   // physical slot c*8: (row=c>>2, pp=c&3)
            *(bf16x8*)(&A_lds[c * 8]) =
                *(const bf16x8*)(Aw2 + ((par * 16 + kt) << 12) + c * 8);
        }
        #pragma unroll
        for (int i = 0; i < 2; ++i) {
            int tsk = i * 256 + tid;
            int n = tsk & 127, kg = tsk >> 7;
            int r = n >> 6, ox = n & 63;
            int row = oy0 + r - 1 + py + ty;
            int col = ox - 1 + px + tx;
            bool ok = (row >= 0) & (row < HIN) & (col >= 0) & (col < HIN);
            const float* xp = xb + (((ci0 + kg * 8) * HIN + row) * HIN + col);
            bf16x8 v;
            #pragma unroll
            for (int q = 0; q < 8; ++q) {
                float f = ok ? xp[q * (HIN * HIN)] : 0.f;
                v[q] = (short)f32_to_bf16(f);
            }
            *(bf16x8*)(&B_lds[n * 32 + kg * 8]) = v;
        }
        __syncthreads();
        const int rl2 = lane & 15, pl2 = lane >> 4;
        bf16x8 af[4], bfr[4];
        #pragma unroll
        for (int f = 0; f < 4; ++f) {
            int ar = wm * 64 + f * 16 + rl2;
            af[f] = *(const bf16x8*)(&A_lds[ar * 32 + ((pl2 ^ ((ar >> 1) & 3)) * 8)]);
            bfr[f] = *(const bf16x8*)(&B_lds[(wn * 64 + f * 16 + rl2) * 32 + pl2 * 8]);
        }
        #pragma unroll
        for (int fm = 0; fm < 4; ++fm)
            #pragma unroll
            for (int fn = 0; fn < 4; ++fn)
                acc[fm][fn] = __builtin_amdgcn_mfma_f32_16x16x32_bf16(
                    af[fm], bfr[fn], acc[fm][fn], 0, 0, 0);
        __syncthreads();
    }
    #pragma unroll
    for (int fm = 0; fm < 4; ++fm) {
        const int co_b = wm * 64 + fm * 16 + (lane >> 4) * 4;
        float bias4[4];
        #pragma unroll
        for (int j = 0; j < 4; ++j) bias4[j] = bv[co_b + j];
        #pragma unroll
        for (int fn = 0; fn < 4; ++fn) {
            int n = wn * 64 + fn * 16 + (lane & 15);
            int s = s0 + n;
            int ox = s & 63, oy = (s >> 6) & 63, bi2 = s >> 12;
            int yy = 2 * oy + py, xx = 2 * ox + px;
            float* op = out + ((size_t)bi2 * 128 * 128 * 128) + (size_t)yy * 128 + xx;
            #pragma unroll
            for (int j = 0; j < 4; ++j)
                op[(size_t)(co_b + j) * (128 * 128)] = acc[fm][fn][j] + bias4[j];
        }
    }
}

extern "C" void kernel_launch(void* const* d_in, const int* in_sizes, int n_in,
                              void* d_out, int out_size, void* d_ws, size_t ws_size,
                              hipStream_t stream) {
    const float* x  = (const float*)d_in[0];
    const float* W  = (const float*)d_in[1];
    const float* bv = (const float*)d_in[2];
    float* out = (float*)d_out;
    unsigned short* Aw2 = (unsigned short*)d_ws;              // 512 KB
    const size_t aw_bytes = 4 * 16 * 128 * 32 * sizeof(unsigned short);
    const size_t xq_bytes = (size_t)NB * 4 * HP * HP * 32 * sizeof(unsigned short);

    if (ws_size >= aw_bytes + xq_bytes) {
        unsigned short* xq = (unsigned short*)((char*)d_ws + aw_bytes);
        prep_kernel<<<1024 + NB * HP, 256, 0, stream>>>(W, x, Aw2, xq);
        upconv4_kernel<<<512, 512, 0, stream>>>(xq, Aw2, bv, out);
    } else {
        prep_kernel<<<1024, 256, 0, stream>>>(W, x, Aw2, (unsigned short*)nullptr);
        upconv_fb_kernel<<<dim3(256, 4), 256, 0, stream>>>(x, Aw2, bv, out);
    }
}